// Round 10
// baseline (617.397 us; speedup 1.0000x reference)
//
#include <hip/hip_runtime.h>
#include <math.h>

#define H_DIM 1024
#define SEG_LEN 18
#define N_SEG 32
#define QUOTA 9
#define GAP_THR 8.0e-4f

typedef _Float16 half8 __attribute__((ext_vector_type(8)));
typedef _Float16 half4 __attribute__((ext_vector_type(4)));
typedef float f32x4 __attribute__((ext_vector_type(4)));
typedef float f32x16 __attribute__((ext_vector_type(16)));

__device__ __forceinline__ void gload_lds16(const void* g, void* l) {
    __builtin_amdgcn_global_load_lds((const __attribute__((address_space(1))) uint32_t*)g,
                                     (__attribute__((address_space(3))) uint32_t*)l,
                                     16, 0, 0);
}

__device__ __forceinline__ float gelu_exact(float h) {
    return 0.5f * h * (1.0f + erff(h * 0.70710678118654752f));
}

// ---- pack W1 [512][1024] fp32 into two layouts ----
// B32 (2 MB): 32x32x16-frag order, 2 exact-split fp16 planes (recheck kernel).
// B16 (1 MB): 16x16x32-frag order, plane-0 only (screen kernel):
//   half-off = (ks*32 + nf16)*512 + lane*8 + j
__global__ void pack_w1_kernel(const float* __restrict__ W1,
                               _Float16* __restrict__ B32,
                               _Float16* __restrict__ B16) {
    const int bid = blockIdx.x, t = threadIdx.x;
    if (bid < 256) {
        int tid = bid * 256 + t;
        int q = tid & 127, n = tid >> 7;
        int kt = q >> 2, ksub = (q >> 1) & 1, hi = q & 1;
        int nb = n >> 8, nf = (n >> 5) & 7, nlo = n & 31;
        const float* src = W1 + (size_t)n * H_DIM + q * 8;
        float4 v0 = *(const float4*)src, v1 = *(const float4*)(src + 4);
        float xs[8] = {v0.x, v0.y, v0.z, v0.w, v1.x, v1.y, v1.z, v1.w};
        half8 h0, h1;
#pragma unroll
        for (int j = 0; j < 8; ++j) {
            _Float16 a = (_Float16)xs[j];
            float r = xs[j] - (float)a;
            h0[j] = a;
            h1[j] = (_Float16)(r * 2048.0f);
        }
        size_t base = (size_t)kt * 32768 + nb * 16384 + ksub * 4096 + nf * 512
                    + (size_t)(hi * 32 + nlo) * 8;
        *(half8*)(B32 + base) = h0;
        *(half8*)(B32 + base + 8192) = h1;
    } else {
        int tid = (bid - 256) * 256 + t;
        int lane = tid & 63, nf = (tid >> 6) & 31, ks = tid >> 11;
        int n = nf * 16 + (lane & 15), k0 = ks * 32 + (lane >> 4) * 8;
        const float* src = W1 + (size_t)n * H_DIM + k0;
        float4 v0 = *(const float4*)src, v1 = *(const float4*)(src + 4);
        float xs[8] = {v0.x, v0.y, v0.z, v0.w, v1.x, v1.y, v1.z, v1.w};
        half8 h0;
#pragma unroll
        for (int j = 0; j < 8; ++j) h0[j] = (_Float16)xs[j];
        *(half8*)(B16 + ((size_t)(ks * 32 + nf)) * 512 + lane * 8) = h0;
    }
}

// ---- stage-1 scorer: 8-phase m201-cadence port ----
// BM=256, BN=256 (nb half), BK=64; 8 waves (2M x 4N), wave tile 128x64.
// LDS: 2 bufs x (A 32 KB + B 32 KB) = 128 KB, frag-packed (conflict-free).
// Per K-tile: 4 phases, each {stage issue | counted vmcnt | cvt+ds_write |
// 12 ds_read | bar | lgkm(0) | setprio(1) 16xMFMA setprio(0) | bar}.
// vmcnt never drains to 0 in the loop (B-DMA spans 3 phases, A-loads ~6).
__global__ __launch_bounds__(512, 1)
void stage1_kernel(const float* __restrict__ X, const _Float16* __restrict__ B16,
                   const float* __restrict__ b1, const float* __restrict__ W2,
                   float* __restrict__ sparts, int tot) {
    __shared__ __align__(16) char smem[131072];
    const int t = threadIdx.x;        // 0..511
    const int w = t >> 6, lane = t & 63;
    const int wr = w >> 2, wc = w & 3;

    // bijective XCD-chunked swizzle (nwg = 1152 % 8 == 0)
    const int nwg = (int)gridDim.x, chunk = nwg >> 3;
    const int logical = ((int)blockIdx.x & 7) * chunk + ((int)blockIdx.x >> 3);
    const int nb = logical & 1;
    const size_t m0 = (size_t)(logical >> 1) * 256;

    // A staging role: thread t -> row (half*128 + (t>>2)), k16-block c_=t&3
    const int r2 = t >> 2;
    const int c_ = t & 3;
    const float* aptr0 = X + (m0 + r2) * H_DIM + c_ * 16;
    const float* aptr1 = aptr0 + (size_t)128 * H_DIM;
    const int ksubw = c_ >> 1;
    const int q0 = (c_ & 1) * 2;
    const int wdsA0 = ((ksubw * 16 + (r2 >> 4)) << 10) + (((r2 & 15) + q0 * 16) << 4);
    const int wdsA1 = ((ksubw * 16 + ((128 + r2) >> 4)) << 10) + (((r2 & 15) + q0 * 16) << 4);

    // B staging: frag-contiguous slabs of B16
    const _Float16* bbase = B16 + ((size_t)nb * 16) * 512 + (size_t)t * 8;

    f32x4 acc[8][4] = {};
    float4 avA[8], avB[8];

#define ISSUE_B_HALF(tb, ksub, BN_)                                             \
    do {                                                                        \
        const _Float16* s_ = bbase + ((size_t)(2 * (tb) + (ksub))) * 16384;     \
        char* d_ = smem + (BN_) + 32768 + (ksub) * 16384 + t * 16;              \
        gload_lds16(s_, d_);                                                    \
        gload_lds16(s_ + 4096, d_ + 8192);                                      \
    } while (0)

#define ISSUE_A_HALF(h, ktgt, AV)                                               \
    do {                                                                        \
        const float* p_ = ((h) ? aptr1 : aptr0) + (ktgt) * 64;                  \
        AV[(h) * 4 + 0] = *(const float4*)(p_);                                 \
        AV[(h) * 4 + 1] = *(const float4*)(p_ + 4);                             \
        AV[(h) * 4 + 2] = *(const float4*)(p_ + 8);                             \
        AV[(h) * 4 + 3] = *(const float4*)(p_ + 12);                            \
    } while (0)

#define CVT_WRITE_A_HALF(h, AV, BN_)                                            \
    do {                                                                        \
        float4 v0 = AV[(h) * 4 + 0], v1 = AV[(h) * 4 + 1];                      \
        float4 v2 = AV[(h) * 4 + 2], v3 = AV[(h) * 4 + 3];                      \
        half8 h0_, h1_;                                                         \
        h0_[0] = (_Float16)v0.x; h0_[1] = (_Float16)v0.y;                       \
        h0_[2] = (_Float16)v0.z; h0_[3] = (_Float16)v0.w;                       \
        h0_[4] = (_Float16)v1.x; h0_[5] = (_Float16)v1.y;                       \
        h0_[6] = (_Float16)v1.z; h0_[7] = (_Float16)v1.w;                       \
        h1_[0] = (_Float16)v2.x; h1_[1] = (_Float16)v2.y;                       \
        h1_[2] = (_Float16)v2.z; h1_[3] = (_Float16)v2.w;                       \
        h1_[4] = (_Float16)v3.x; h1_[5] = (_Float16)v3.y;                       \
        h1_[6] = (_Float16)v3.z; h1_[7] = (_Float16)v3.w;                       \
        int wo_ = (h) ? wdsA1 : wdsA0;                                          \
        *(half8*)(smem + (BN_) + wo_) = h0_;                                    \
        *(half8*)(smem + (BN_) + wo_ + 256) = h1_;                              \
    } while (0)

#define PHASE_MFMA(BC, qm, qn)                                                  \
    do {                                                                        \
        half8 af[2][4], bf[2][2];                                               \
        _Pragma("unroll") for (int ks_ = 0; ks_ < 2; ++ks_) {                   \
            _Pragma("unroll") for (int i_ = 0; i_ < 4; ++i_)                    \
                af[ks_][i_] = *(const half8*)(smem + (BC)                       \
                    + ((ks_ * 16 + wr * 8 + (qm) * 4 + i_) << 10) + lane * 16); \
            _Pragma("unroll") for (int j_ = 0; j_ < 2; ++j_)                    \
                bf[ks_][j_] = *(const half8*)(smem + (BC) + 32768               \
                    + ((ks_ * 16 + wc * 4 + (qn) * 2 + j_) << 10) + lane * 16); \
        }                                                                       \
        __builtin_amdgcn_s_barrier();                                           \
        asm volatile("s_waitcnt lgkmcnt(0)" ::: "memory");                      \
        __builtin_amdgcn_sched_barrier(0);                                      \
        __builtin_amdgcn_s_setprio(1);                                          \
        _Pragma("unroll") for (int ks_ = 0; ks_ < 2; ++ks_)                     \
            _Pragma("unroll") for (int i_ = 0; i_ < 4; ++i_)                    \
                _Pragma("unroll") for (int j_ = 0; j_ < 2; ++j_)                \
                    acc[(qm) * 4 + i_][(qn) * 2 + j_] =                         \
                        __builtin_amdgcn_mfma_f32_16x16x32_f16(                 \
                            af[ks_][i_], bf[ks_][j_],                           \
                            acc[(qm) * 4 + i_][(qn) * 2 + j_], 0, 0, 0);        \
        __builtin_amdgcn_s_setprio(0);                                          \
        __builtin_amdgcn_s_barrier();                                           \
    } while (0)

#define K_TILE(kt, BC, BN_, AVC, AVN)                                           \
    do {                                                                        \
        const int tb_ = ((kt) + 1 < 16) ? (kt) + 1 : 15;                        \
        const int ta_ = ((kt) + 2 < 16) ? (kt) + 2 : 15;                        \
        /* P1: +B'h0(2) -> 10 out; vmcnt(6) completes A'h0 */                   \
        ISSUE_B_HALF(tb_, 0, BN_);                                              \
        __builtin_amdgcn_sched_barrier(0);                                      \
        asm volatile("s_waitcnt vmcnt(6)" ::: "memory");                        \
        __builtin_amdgcn_sched_barrier(0);                                      \
        CVT_WRITE_A_HALF(0, AVC, BN_);                                          \
        PHASE_MFMA(BC, 0, 0);                                                   \
        /* P2: +B'h1(2)+A''h0(4) -> 12 out; vmcnt(8) completes A'h1 */          \
        ISSUE_B_HALF(tb_, 1, BN_);                                              \
        ISSUE_A_HALF(0, ta_, AVN);                                              \
        __builtin_amdgcn_sched_barrier(0);                                      \
        asm volatile("s_waitcnt vmcnt(8)" ::: "memory");                        \
        __builtin_amdgcn_sched_barrier(0);                                      \
        CVT_WRITE_A_HALF(1, AVC, BN_);                                          \
        PHASE_MFMA(BC, 0, 1);                                                   \
        /* P3: +A''h1(4) -> 12 out; no wait */                                  \
        ISSUE_A_HALF(1, ta_, AVN);                                              \
        __builtin_amdgcn_sched_barrier(0);                                      \
        PHASE_MFMA(BC, 1, 0);                                                   \
        /* P4: vmcnt(8) completes B'(4); A''(8) spans into next tile */         \
        asm volatile("s_waitcnt vmcnt(8)" ::: "memory");                        \
        __builtin_amdgcn_sched_barrier(0);                                      \
        PHASE_MFMA(BC, 1, 1);                                                   \
    } while (0)

    // ---- prologue: stage tile 0 fully; leave A(1) loads (8) in flight ----
    ISSUE_B_HALF(0, 0, 0);
    ISSUE_B_HALF(0, 1, 0);
    ISSUE_A_HALF(0, 0, avB);
    ISSUE_A_HALF(1, 0, avB);
    __builtin_amdgcn_sched_barrier(0);
    asm volatile("s_waitcnt vmcnt(0)" ::: "memory");
    __builtin_amdgcn_sched_barrier(0);
    CVT_WRITE_A_HALF(0, avB, 0);
    CVT_WRITE_A_HALF(1, avB, 0);
    ISSUE_A_HALF(0, 1, avA);
    ISSUE_A_HALF(1, 1, avA);
    __builtin_amdgcn_sched_barrier(0);
    asm volatile("s_waitcnt lgkmcnt(0)" ::: "memory");
    __builtin_amdgcn_sched_barrier(0);
    __builtin_amdgcn_s_barrier();

    for (int kt = 0; kt < 16; kt += 2) {
        K_TILE(kt,     0,     65536, avA, avB);
        K_TILE(kt + 1, 65536, 0,     avB, avA);
    }

    // ---- drain tail staging (clamped tiles' DMA targets buf0) ----
    asm volatile("s_waitcnt vmcnt(0) lgkmcnt(0)" ::: "memory");
    __builtin_amdgcn_sched_barrier(0);
    __syncthreads();

    // ---- epilogue: h = acc + b1; gelu; *W2; per-row partial over 256 cols ----
    float* red = (float*)smem;   // [256][65]
    float b1v[4], w2v[4];
#pragma unroll
    for (int nf = 0; nf < 4; ++nf) {
        int c = nb * 256 + wc * 64 + nf * 16 + (lane & 15);
        b1v[nf] = b1[c];
        w2v[nf] = W2[c];
    }
#pragma unroll
    for (int mf = 0; mf < 8; ++mf) {
#pragma unroll
        for (int i = 0; i < 4; ++i) {
            float s = 0.f;
#pragma unroll
            for (int nf = 0; nf < 4; ++nf) {
                float h = acc[mf][nf][i] + b1v[nf];
                s = fmaf(gelu_exact(h), w2v[nf], s);
            }
            int row = wr * 128 + mf * 16 + (lane >> 4) * 4 + i;
            red[row * 65 + wc * 16 + (lane & 15)] = s;
        }
    }
    __syncthreads();
    if (t < 256) {
        float s = 0.f;
#pragma unroll
        for (int c = 0; c < 64; ++c) s += red[t * 65 + c];
        sparts[(size_t)nb * tot + m0 + t] = s;
    }
}

// ---- flag + provisional select from screen scores ----
__global__ void flag_select_kernel(const float* __restrict__ sparts, int tot,
                                   int* __restrict__ sel_buf,
                                   int* __restrict__ flag_list,
                                   int* __restrict__ counter, int N, int nseg_tot) {
    int seg = blockIdx.x * 256 + threadIdx.x;
    if (seg >= nseg_tot) return;
    int b = seg >> 5, s = seg & 31;
    size_t base = (size_t)b * N + s * SEG_LEN;
    float sc[SEG_LEN];
#pragma unroll
    for (int j = 0; j < SEG_LEN; ++j) sc[j] = sparts[base + j] + sparts[base + j + tot];
    unsigned mask = 0;
    float best9 = 0.f;
    for (int it = 0; it < QUOTA; ++it) {
        float best = 0.f; int bi = 0; bool found = false;
        for (int i = 0; i < SEG_LEN; ++i) if (!((mask >> i) & 1u)) {
            if (!found || sc[i] > best) { best = sc[i]; bi = i; found = true; }
        }
        mask |= 1u << bi;
        best9 = best;
    }
    float best10 = 0.f; bool f10 = false;
    for (int i = 0; i < SEG_LEN; ++i) if (!((mask >> i) & 1u)) {
        if (!f10 || sc[i] > best10) { best10 = sc[i]; f10 = true; }
    }
    if (best9 - best10 > GAP_THR) {
        int c = 0;
        for (int i = 0; i < SEG_LEN; ++i)
            if ((mask >> i) & 1u) sel_buf[(size_t)seg * QUOTA + (c++)] = i;
    } else {
        int p = atomicAdd(counter, 1);
        flag_list[p] = seg;
    }
}

// ---- exact recheck (fp16-split 3-pass, proven numerics) of flagged segments ----
__global__ __launch_bounds__(512, 2)
void recheck_kernel(const float* __restrict__ X, const _Float16* __restrict__ B32,
                    const float* __restrict__ b1, const float* __restrict__ W2,
                    const int* __restrict__ flag_list, const int* __restrict__ counter,
                    int* __restrict__ sel_buf, int N) {
    const int count = *counter;
    const int jb = blockIdx.x;
    if (jb * 3 >= count) return;
    __shared__ __align__(16) char smem[73728];
    const int t = threadIdx.x, w = t >> 6, lane = t & 63;

    const int r_ = t >> 3, kq8 = t & 7;
    int q = r_ / 18, rr = r_ % 18;
    if (r_ >= 54) { q = 2; rr = 0; }
    int li = jb * 3 + q; if (li >= count) li = count - 1;
    const int sg = flag_list[li];
    const float* aRow = X + ((size_t)(sg >> 5) * N + (sg & 31) * SEG_LEN + rr) * H_DIM + kq8 * 4;
    const int rg = r_ >> 5, aks = kq8 >> 2, ahi = (kq8 >> 1) & 1;
    const int aoff = (rg * 2 + aks) * 1024 + (ahi * 32 + (r_ & 31)) * 16 + (kq8 & 1) * 8;

    f32x16 acc1[2][2] = {};
    f32x16 acc2[2][2] = {};
    float4 av = *(const float4*)aRow;

    for (int kt = 0; kt < 32; ++kt) {
#pragma unroll
        for (int r8 = 0; r8 < 8; ++r8) {
            int idx = r8 * 512 + t;
            gload_lds16(B32 + (size_t)kt * 32768 + (size_t)idx * 8,
                        smem + 8192 + (size_t)idx * 16);
        }
        {
            float xs[4] = {av.x, av.y, av.z, av.w};
            half4 h0, h1;
#pragma unroll
            for (int j = 0; j < 4; ++j) {
                _Float16 a = (_Float16)xs[j];
                float r = xs[j] - (float)a;
                h0[j] = a;
                h1[j] = (_Float16)(r * 2048.0f);
            }
            *(half4*)(smem + aoff) = h0;
            *(half4*)(smem + 4096 + aoff) = h1;
        }
        int ktn = kt < 31 ? kt + 1 : 31;
        av = *(const float4*)(aRow + ktn * 32);
        asm volatile("s_waitcnt vmcnt(1) lgkmcnt(0)" ::: "memory");
        __builtin_amdgcn_sched_barrier(0);
        __builtin_amdgcn_s_barrier();

        half8 a0[4], a1[4], b0[4], b1f[4];
#pragma unroll
        for (int mf = 0; mf < 2; ++mf)
#pragma unroll
            for (int ks2 = 0; ks2 < 2; ++ks2) {
                a0[mf * 2 + ks2] = *(const half8*)(smem + (mf * 2 + ks2) * 1024 + lane * 16);
                a1[mf * 2 + ks2] = *(const half8*)(smem + 4096 + (mf * 2 + ks2) * 1024 + lane * 16);
            }
        const char* bb = smem + 8192 + (w >> 2) * 32768;
#pragma unroll
        for (int nfl = 0; nfl < 2; ++nfl)
#pragma unroll
            for (int ks2 = 0; ks2 < 2; ++ks2) {
                b0[nfl * 2 + ks2]  = *(const half8*)(bb + ks2 * 8192 + ((w & 3) * 2 + nfl) * 1024 + lane * 16);
                b1f[nfl * 2 + ks2] = *(const half8*)(bb + 16384 + ks2 * 8192 + ((w & 3) * 2 + nfl) * 1024 + lane * 16);
            }
        __builtin_amdgcn_s_setprio(1);
#pragma unroll
        for (int mf = 0; mf < 2; ++mf)
#pragma unroll
            for (int nfl = 0; nfl < 2; ++nfl)
#pragma unroll
                for (int ks2 = 0; ks2 < 2; ++ks2)
                    acc1[mf][nfl] = __builtin_amdgcn_mfma_f32_32x32x16_f16(
                        a0[mf * 2 + ks2], b0[nfl * 2 + ks2], acc1[mf][nfl], 0, 0, 0);
#pragma unroll
        for (int mf = 0; mf < 2; ++mf)
#pragma unroll
            for (int nfl = 0; nfl < 2; ++nfl)
#pragma unroll
                for (int ks2 = 0; ks2 < 2; ++ks2)
                    acc2[mf][nfl] = __builtin_amdgcn_mfma_f32_32x32x16_f16(
                        a0[mf * 2 + ks2], b1f[nfl * 2 + ks2], acc2[mf][nfl], 0, 0, 0);
#pragma unroll
        for (int mf = 0; mf < 2; ++mf)
#pragma unroll
            for (int nfl = 0; nfl < 2; ++nfl)
#pragma unroll
                for (int ks2 = 0; ks2 < 2; ++ks2)
                    acc2[mf][nfl] = __builtin_amdgcn_mfma_f32_32x32x16_f16(
                        a1[mf * 2 + ks2], b0[nfl * 2 + ks2], acc2[mf][nfl], 0, 0, 0);
        __builtin_amdgcn_s_setprio(0);
        __builtin_amdgcn_s_barrier();
    }

    __syncthreads();
    float* red = (float*)smem;                 // [8][64][33]
    float b1v[2], w2v[2];
#pragma unroll
    for (int nfl = 0; nfl < 2; ++nfl) {
        int c = (w >> 2) * 256 + ((w & 3) * 2 + nfl) * 32 + (lane & 31);
        b1v[nfl] = b1[c];
        w2v[nfl] = W2[c];
    }
#pragma unroll
    for (int mf = 0; mf < 2; ++mf)
#pragma unroll
        for (int i = 0; i < 16; ++i) {
            float s = 0.f;
#pragma unroll
            for (int nfl = 0; nfl < 2; ++nfl) {
                float h = acc1[mf][nfl][i] + acc2[mf][nfl][i] * (1.0f / 2048.0f) + b1v[nfl];
                s = fmaf(gelu_exact(h), w2v[nfl], s);
            }
            int row = mf * 32 + (i & 3) + 8 * (i >> 2) + 4 * (lane >> 5);
            red[(w * 64 + row) * 33 + (lane & 31)] = s;
        }
    __syncthreads();
    float* sx = (float*)(smem + 67584);        // [64]
    if (t < 64) {
        float s = 0.f;
        for (int ww = 0; ww < 8; ++ww)
#pragma unroll
            for (int lc = 0; lc < 32; ++lc) s += red[(ww * 64 + t) * 33 + lc];
        sx[t] = s;
    }
    __syncthreads();
    if (t < 3 && jb * 3 + t < count) {
        int sg2 = flag_list[jb * 3 + t];
        const float* sv = sx + t * SEG_LEN;
        unsigned mask = 0;
        for (int it = 0; it < QUOTA; ++it) {
            float best = 0.f; int bi = 0; bool found = false;
            for (int i = 0; i < SEG_LEN; ++i) if (!((mask >> i) & 1u)) {
                if (!found || sv[i] > best) { best = sv[i]; bi = i; found = true; }
            }
            mask |= 1u << bi;
        }
        int c = 0;
        for (int i = 0; i < SEG_LEN; ++i)
            if ((mask >> i) & 1u) sel_buf[(size_t)sg2 * QUOTA + (c++)] = i;
    }
}

// ---- final gather of selected rows ----
__global__ void gather_kernel(const float* __restrict__ X, const int* __restrict__ sel_buf,
                              float* __restrict__ out, int N) {
    const int seg = blockIdx.x, b = blockIdx.y, t = threadIdx.x;
    const int* sel = sel_buf + ((size_t)b * N_SEG + seg) * QUOTA;
    const float4* xb = (const float4*)X + ((size_t)b * N + seg * SEG_LEN) * (H_DIM / 4);
    float4* ob = (float4*)out + ((size_t)b * N_SEG * QUOTA + seg * QUOTA) * (H_DIM / 4);
#pragma unroll
    for (int j = 0; j < QUOTA; ++j) {
        int r = sel[j];
        ob[(size_t)j * (H_DIM / 4) + t] = xb[(size_t)r * (H_DIM / 4) + t];
    }
}

extern "C" void kernel_launch(void* const* d_in, const int* in_sizes, int n_in,
                              void* d_out, int out_size, void* d_ws, size_t ws_size,
                              hipStream_t stream) {
    const float* X  = (const float*)d_in[0];
    const float* W1 = (const float*)d_in[1];
    const float* b1 = (const float*)d_in[2];
    const float* W2 = (const float*)d_in[3];
    float* out = (float*)d_out;

    const int Hh = in_sizes[2];                        // 512
    const int H  = Hh * 2;                             // 1024
    const long long TOT = (long long)in_sizes[0] / H;  // 147456 tokens
    const int B = 256;
    const int N = (int)(TOT / B);                      // 576
    const int nseg_tot = B * N_SEG;                    // 8192

    char* ws = (char*)d_ws;
    _Float16* B32 = (_Float16*)(ws + 0);               // 2 MB
    _Float16* B16 = (_Float16*)(ws + 2097152);         // 1 MB
    float* sparts = (float*)(ws + 3145728);            // 2*TOT f32
    int* sel_buf  = (int*)(ws + 4325376);              // 8192*9
    int* flag_list= (int*)(ws + 4620288);              // 8192
    int* counter  = (int*)(ws + 4653056);

    hipMemsetAsync(counter, 0, 16, stream);

    hipLaunchKernelGGL(pack_w1_kernel, dim3(512), dim3(256), 0, stream, W1, B32, B16);

    const int nwg = (int)(TOT / 256) * 2;              // 1152, divisible by 8
    hipLaunchKernelGGL(stage1_kernel, dim3(nwg), dim3(512), 0, stream,
                       X, B16, b1, W2, sparts, (int)TOT);

    hipLaunchKernelGGL(flag_select_kernel, dim3((nseg_tot + 255) / 256), dim3(256), 0, stream,
                       sparts, (int)TOT, sel_buf, flag_list, counter, N, nseg_tot);

    hipLaunchKernelGGL(recheck_kernel, dim3((nseg_tot + 2) / 3), dim3(512), 0, stream,
                       X, B32, b1, W2, flag_list, counter, sel_buf, N);

    hipLaunchKernelGGL(gather_kernel, dim3(N_SEG, B), dim3(256), 0, stream,
                       X, sel_buf, out, N);
}

// Round 11
// 570.631 us; speedup vs baseline: 1.0820x; 1.0820x over previous
//
#include <hip/hip_runtime.h>
#include <math.h>

#define H_DIM 1024
#define SEG_LEN 18
#define N_SEG 32
#define QUOTA 9
#define GAP_THR 8.0e-4f

typedef _Float16 half8 __attribute__((ext_vector_type(8)));
typedef _Float16 half4 __attribute__((ext_vector_type(4)));
typedef float f32x4 __attribute__((ext_vector_type(4)));
typedef float f32x16 __attribute__((ext_vector_type(16)));

__device__ __forceinline__ void gload_lds16(const void* g, void* l) {
    __builtin_amdgcn_global_load_lds((const __attribute__((address_space(1))) uint32_t*)g,
                                     (__attribute__((address_space(3))) uint32_t*)l,
                                     16, 0, 0);
}

__device__ __forceinline__ float gelu_exact(float h) {
    return 0.5f * h * (1.0f + erff(h * 0.70710678118654752f));
}

// ---- pack W1 [512][1024] fp32 into two layouts ----
// B32 (2 MB): 32x32x16-frag order, 2 exact-split fp16 planes (recheck kernel).
// B16 (1 MB): 16x16x32-frag order, plane-0 only (screen kernel):
//   half-off = (ks*32 + nf16)*512 + lane*8 + j   (each frag = 1 KB contiguous)
__global__ void pack_w1_kernel(const float* __restrict__ W1,
                               _Float16* __restrict__ B32,
                               _Float16* __restrict__ B16) {
    const int bid = blockIdx.x, t = threadIdx.x;
    if (bid < 256) {
        int tid = bid * 256 + t;
        int q = tid & 127, n = tid >> 7;
        int kt = q >> 2, ksub = (q >> 1) & 1, hi = q & 1;
        int nb = n >> 8, nf = (n >> 5) & 7, nlo = n & 31;
        const float* src = W1 + (size_t)n * H_DIM + q * 8;
        float4 v0 = *(const float4*)src, v1 = *(const float4*)(src + 4);
        float xs[8] = {v0.x, v0.y, v0.z, v0.w, v1.x, v1.y, v1.z, v1.w};
        half8 h0, h1;
#pragma unroll
        for (int j = 0; j < 8; ++j) {
            _Float16 a = (_Float16)xs[j];
            float r = xs[j] - (float)a;
            h0[j] = a;
            h1[j] = (_Float16)(r * 2048.0f);
        }
        size_t base = (size_t)kt * 32768 + nb * 16384 + ksub * 4096 + nf * 512
                    + (size_t)(hi * 32 + nlo) * 8;
        *(half8*)(B32 + base) = h0;
        *(half8*)(B32 + base + 8192) = h1;
    } else {
        int tid = (bid - 256) * 256 + t;
        int lane = tid & 63, nf = (tid >> 6) & 31, ks = tid >> 11;
        int n = nf * 16 + (lane & 15), k0 = ks * 32 + (lane >> 4) * 8;
        const float* src = W1 + (size_t)n * H_DIM + k0;
        float4 v0 = *(const float4*)src, v1 = *(const float4*)(src + 4);
        float xs[8] = {v0.x, v0.y, v0.z, v0.w, v1.x, v1.y, v1.z, v1.w};
        half8 h0;
#pragma unroll
        for (int j = 0; j < 8; ++j) h0[j] = (_Float16)xs[j];
        *(half8*)(B16 + ((size_t)(ks * 32 + nf)) * 512 + lane * 8) = h0;
    }
}

// ---- stage-1 scorer: A via tiny LDS, B DIRECT from L2 in fragment order ----
// 64 rows x 256 cols (nb half), 4 waves of 64x64. LDS = As dbuf 8 KB only
// (red overlays, 17.4 KB total) -> 4 blocks/CU; 128-VGPR pin -> 4 waves/SIMD.
// Per K-step: 2 A-gloads + 4 B-gloads (reg prefetch) + cvt + 1 ds_write +
// 4 ds_read + 16 MFMA + ONE lgkm-only barrier (no vmcnt at barrier at all).
__global__ __launch_bounds__(256, 4)
void stage1_kernel(const float* __restrict__ X, const _Float16* __restrict__ B16,
                   const float* __restrict__ b1, const float* __restrict__ W2,
                   float* __restrict__ sparts, int tot) {
    __shared__ __align__(16) char smem[17408];   // As 2x4KB; red[4][64][17] overlays
    const int t = threadIdx.x, w = t >> 6, lane = t & 63;
    const int nb = blockIdx.y;
    const size_t m0 = (size_t)blockIdx.x * 64;

    // A staging: thread t -> row w*16+(t&15), k-octet (t>>4)&3; slot = lane
    const int arow = w * 16 + (t & 15);
    const int aq = (t >> 4) & 3;
    const float* aptr = X + (m0 + arow) * H_DIM + aq * 8;
    // B direct: frag (ks, nb*16 + w*4 + j) at bptr + ks*16384 + j*512 (halves)
    const _Float16* bptr = B16 + ((size_t)(nb * 16 + w * 4)) * 512 + lane * 8;

    f32x4 acc[4][4] = {};
    float4 av0, av1;
    half8 bc0, bc1, bc2, bc3, bn0, bn1, bn2, bn3;

#define S1_CONVERT(buf)                                                         \
    do {                                                                        \
        float xs[8] = {av0.x, av0.y, av0.z, av0.w, av1.x, av1.y, av1.z, av1.w}; \
        half8 h0;                                                               \
        _Pragma("unroll") for (int j = 0; j < 8; ++j) h0[j] = (_Float16)xs[j];  \
        *(half8*)(smem + (buf) * 4096 + w * 1024 + lane * 16) = h0;             \
    } while (0)

    // ---- prologue ----
    av0 = *(const float4*)aptr;
    av1 = *(const float4*)(aptr + 4);
    bc0 = *(const half8*)(bptr);
    bc1 = *(const half8*)(bptr + 512);
    bc2 = *(const half8*)(bptr + 1024);
    bc3 = *(const half8*)(bptr + 1536);
    S1_CONVERT(0);                    // waits the 2 A-loads only
    av0 = *(const float4*)(aptr + 32);
    av1 = *(const float4*)(aptr + 36);
    asm volatile("s_waitcnt lgkmcnt(0)" ::: "memory");
    __builtin_amdgcn_sched_barrier(0);
    __builtin_amdgcn_s_barrier();

    int cur = 0;
    for (int ks = 0; ks < 32; ++ks) {
        const int nxt = cur ^ 1;
        if (ks < 31) {
            const _Float16* bp = bptr + (size_t)(ks + 1) * 16384;
            bn0 = *(const half8*)(bp);
            bn1 = *(const half8*)(bp + 512);
            bn2 = *(const half8*)(bp + 1024);
            bn3 = *(const half8*)(bp + 1536);
            S1_CONVERT(nxt);                 // consumes av = A(ks+1)
            if (ks < 30) {
                av0 = *(const float4*)(aptr + (ks + 2) * 32);
                av1 = *(const float4*)(aptr + (ks + 2) * 32 + 4);
            }
        }
        // fragment reads in 2 half-groups (limits live regs)
        half8 a0 = *(const half8*)(smem + cur * 4096 + 0 * 1024 + lane * 16);
        half8 a1 = *(const half8*)(smem + cur * 4096 + 1 * 1024 + lane * 16);
        __builtin_amdgcn_s_setprio(1);
        acc[0][0] = __builtin_amdgcn_mfma_f32_16x16x32_f16(a0, bc0, acc[0][0], 0, 0, 0);
        acc[0][1] = __builtin_amdgcn_mfma_f32_16x16x32_f16(a0, bc1, acc[0][1], 0, 0, 0);
        acc[0][2] = __builtin_amdgcn_mfma_f32_16x16x32_f16(a0, bc2, acc[0][2], 0, 0, 0);
        acc[0][3] = __builtin_amdgcn_mfma_f32_16x16x32_f16(a0, bc3, acc[0][3], 0, 0, 0);
        acc[1][0] = __builtin_amdgcn_mfma_f32_16x16x32_f16(a1, bc0, acc[1][0], 0, 0, 0);
        acc[1][1] = __builtin_amdgcn_mfma_f32_16x16x32_f16(a1, bc1, acc[1][1], 0, 0, 0);
        acc[1][2] = __builtin_amdgcn_mfma_f32_16x16x32_f16(a1, bc2, acc[1][2], 0, 0, 0);
        acc[1][3] = __builtin_amdgcn_mfma_f32_16x16x32_f16(a1, bc3, acc[1][3], 0, 0, 0);
        half8 a2 = *(const half8*)(smem + cur * 4096 + 2 * 1024 + lane * 16);
        half8 a3 = *(const half8*)(smem + cur * 4096 + 3 * 1024 + lane * 16);
        acc[2][0] = __builtin_amdgcn_mfma_f32_16x16x32_f16(a2, bc0, acc[2][0], 0, 0, 0);
        acc[2][1] = __builtin_amdgcn_mfma_f32_16x16x32_f16(a2, bc1, acc[2][1], 0, 0, 0);
        acc[2][2] = __builtin_amdgcn_mfma_f32_16x16x32_f16(a2, bc2, acc[2][2], 0, 0, 0);
        acc[2][3] = __builtin_amdgcn_mfma_f32_16x16x32_f16(a2, bc3, acc[2][3], 0, 0, 0);
        acc[3][0] = __builtin_amdgcn_mfma_f32_16x16x32_f16(a3, bc0, acc[3][0], 0, 0, 0);
        acc[3][1] = __builtin_amdgcn_mfma_f32_16x16x32_f16(a3, bc1, acc[3][1], 0, 0, 0);
        acc[3][2] = __builtin_amdgcn_mfma_f32_16x16x32_f16(a3, bc2, acc[3][2], 0, 0, 0);
        acc[3][3] = __builtin_amdgcn_mfma_f32_16x16x32_f16(a3, bc3, acc[3][3], 0, 0, 0);
        __builtin_amdgcn_s_setprio(0);

        if (ks < 31) {
            asm volatile("s_waitcnt lgkmcnt(0)" ::: "memory");  // A writes + frag reads
            __builtin_amdgcn_sched_barrier(0);
            __builtin_amdgcn_s_barrier();
        }
        bc0 = bn0; bc1 = bn1; bc2 = bn2; bc3 = bn3;
        cur = nxt;
    }

    // epilogue: h = acc + b1; gelu; *W2; reduce 256 cols -> partial scores
    __syncthreads();
    float* red = (float*)smem;  // [4][64][17]
    const int hi = lane >> 4, lc = lane & 15;
    float b1v[4], w2v[4];
#pragma unroll
    for (int nf = 0; nf < 4; ++nf) {
        int c = nb * 256 + w * 64 + nf * 16 + lc;
        b1v[nf] = b1[c];
        w2v[nf] = W2[c];
    }
#pragma unroll
    for (int mf = 0; mf < 4; ++mf) {
#pragma unroll
        for (int i = 0; i < 4; ++i) {
            float s = 0.f;
#pragma unroll
            for (int nf = 0; nf < 4; ++nf) {
                float h = acc[mf][nf][i] + b1v[nf];
                s = fmaf(gelu_exact(h), w2v[nf], s);
            }
            red[(w * 64 + mf * 16 + hi * 4 + i) * 17 + lc] = s;
        }
    }
    __syncthreads();
    if (t < 64) {
        float s = 0.f;
#pragma unroll
        for (int ww = 0; ww < 4; ++ww)
#pragma unroll
            for (int c = 0; c < 16; ++c) s += red[(ww * 64 + t) * 17 + c];
        sparts[(size_t)nb * tot + m0 + t] = s;
    }
}

// ---- flag + provisional select from screen scores ----
__global__ void flag_select_kernel(const float* __restrict__ sparts, int tot,
                                   int* __restrict__ sel_buf,
                                   int* __restrict__ flag_list,
                                   int* __restrict__ counter, int N, int nseg_tot) {
    int seg = blockIdx.x * 256 + threadIdx.x;
    if (seg >= nseg_tot) return;
    int b = seg >> 5, s = seg & 31;
    size_t base = (size_t)b * N + s * SEG_LEN;
    float sc[SEG_LEN];
#pragma unroll
    for (int j = 0; j < SEG_LEN; ++j) sc[j] = sparts[base + j] + sparts[base + j + tot];
    unsigned mask = 0;
    float best9 = 0.f;
    for (int it = 0; it < QUOTA; ++it) {
        float best = 0.f; int bi = 0; bool found = false;
        for (int i = 0; i < SEG_LEN; ++i) if (!((mask >> i) & 1u)) {
            if (!found || sc[i] > best) { best = sc[i]; bi = i; found = true; }
        }
        mask |= 1u << bi;
        best9 = best;
    }
    float best10 = 0.f; bool f10 = false;
    for (int i = 0; i < SEG_LEN; ++i) if (!((mask >> i) & 1u)) {
        if (!f10 || sc[i] > best10) { best10 = sc[i]; f10 = true; }
    }
    if (best9 - best10 > GAP_THR) {
        int c = 0;
        for (int i = 0; i < SEG_LEN; ++i)
            if ((mask >> i) & 1u) sel_buf[(size_t)seg * QUOTA + (c++)] = i;
    } else {
        int p = atomicAdd(counter, 1);
        flag_list[p] = seg;
    }
}

// ---- exact recheck (fp16-split 3-pass, proven numerics) of flagged segments ----
__global__ __launch_bounds__(512, 2)
void recheck_kernel(const float* __restrict__ X, const _Float16* __restrict__ B32,
                    const float* __restrict__ b1, const float* __restrict__ W2,
                    const int* __restrict__ flag_list, const int* __restrict__ counter,
                    int* __restrict__ sel_buf, int N) {
    const int count = *counter;
    const int jb = blockIdx.x;
    if (jb * 3 >= count) return;
    __shared__ __align__(16) char smem[73728];
    const int t = threadIdx.x, w = t >> 6, lane = t & 63;

    const int r_ = t >> 3, kq8 = t & 7;
    int q = r_ / 18, rr = r_ % 18;
    if (r_ >= 54) { q = 2; rr = 0; }
    int li = jb * 3 + q; if (li >= count) li = count - 1;
    const int sg = flag_list[li];
    const float* aRow = X + ((size_t)(sg >> 5) * N + (sg & 31) * SEG_LEN + rr) * H_DIM + kq8 * 4;
    const int rg = r_ >> 5, aks = kq8 >> 2, ahi = (kq8 >> 1) & 1;
    const int aoff = (rg * 2 + aks) * 1024 + (ahi * 32 + (r_ & 31)) * 16 + (kq8 & 1) * 8;

    f32x16 acc1[2][2] = {};
    f32x16 acc2[2][2] = {};
    float4 av = *(const float4*)aRow;

    for (int kt = 0; kt < 32; ++kt) {
#pragma unroll
        for (int r8 = 0; r8 < 8; ++r8) {
            int idx = r8 * 512 + t;
            gload_lds16(B32 + (size_t)kt * 32768 + (size_t)idx * 8,
                        smem + 8192 + (size_t)idx * 16);
        }
        {
            float xs[4] = {av.x, av.y, av.z, av.w};
            half4 h0, h1;
#pragma unroll
            for (int j = 0; j < 4; ++j) {
                _Float16 a = (_Float16)xs[j];
                float r = xs[j] - (float)a;
                h0[j] = a;
                h1[j] = (_Float16)(r * 2048.0f);
            }
            *(half4*)(smem + aoff) = h0;
            *(half4*)(smem + 4096 + aoff) = h1;
        }
        int ktn = kt < 31 ? kt + 1 : 31;
        av = *(const float4*)(aRow + ktn * 32);
        asm volatile("s_waitcnt vmcnt(1) lgkmcnt(0)" ::: "memory");
        __builtin_amdgcn_sched_barrier(0);
        __builtin_amdgcn_s_barrier();

        half8 a0[4], a1[4], b0[4], b1f[4];
#pragma unroll
        for (int mf = 0; mf < 2; ++mf)
#pragma unroll
            for (int ks2 = 0; ks2 < 2; ++ks2) {
                a0[mf * 2 + ks2] = *(const half8*)(smem + (mf * 2 + ks2) * 1024 + lane * 16);
                a1[mf * 2 + ks2] = *(const half8*)(smem + 4096 + (mf * 2 + ks2) * 1024 + lane * 16);
            }
        const char* bb = smem + 8192 + (w >> 2) * 32768;
#pragma unroll
        for (int nfl = 0; nfl < 2; ++nfl)
#pragma unroll
            for (int ks2 = 0; ks2 < 2; ++ks2) {
                b0[nfl * 2 + ks2]  = *(const half8*)(bb + ks2 * 8192 + ((w & 3) * 2 + nfl) * 1024 + lane * 16);
                b1f[nfl * 2 + ks2] = *(const half8*)(bb + 16384 + ks2 * 8192 + ((w & 3) * 2 + nfl) * 1024 + lane * 16);
            }
        __builtin_amdgcn_s_setprio(1);
#pragma unroll
        for (int mf = 0; mf < 2; ++mf)
#pragma unroll
            for (int nfl = 0; nfl < 2; ++nfl)
#pragma unroll
                for (int ks2 = 0; ks2 < 2; ++ks2)
                    acc1[mf][nfl] = __builtin_amdgcn_mfma_f32_32x32x16_f16(
                        a0[mf * 2 + ks2], b0[nfl * 2 + ks2], acc1[mf][nfl], 0, 0, 0);
#pragma unroll
        for (int mf = 0; mf < 2; ++mf)
#pragma unroll
            for (int nfl = 0; nfl < 2; ++nfl)
#pragma unroll
                for (int ks2 = 0; ks2 < 2; ++ks2)
                    acc2[mf][nfl] = __builtin_amdgcn_mfma_f32_32x32x16_f16(
                        a0[mf * 2 + ks2], b1f[nfl * 2 + ks2], acc2[mf][nfl], 0, 0, 0);
#pragma unroll
        for (int mf = 0; mf < 2; ++mf)
#pragma unroll
            for (int nfl = 0; nfl < 2; ++nfl)
#pragma unroll
                for (int ks2 = 0; ks2 < 2; ++ks2)
                    acc2[mf][nfl] = __builtin_amdgcn_mfma_f32_32x32x16_f16(
                        a1[mf * 2 + ks2], b0[nfl * 2 + ks2], acc2[mf][nfl], 0, 0, 0);
        __builtin_amdgcn_s_setprio(0);
        __builtin_amdgcn_s_barrier();
    }

    __syncthreads();
    float* red = (float*)smem;                 // [8][64][33]
    float b1v[2], w2v[2];
#pragma unroll
    for (int nfl = 0; nfl < 2; ++nfl) {
        int c = (w >> 2) * 256 + ((w & 3) * 2 + nfl) * 32 + (lane & 31);
        b1v[nfl] = b1[c];
        w2v[nfl] = W2[c];
    }
#pragma unroll
    for (int mf = 0; mf < 2; ++mf)
#pragma unroll
        for (int i = 0; i < 16; ++i) {
            float s = 0.f;
#pragma unroll
            for (int nfl = 0; nfl < 2; ++nfl) {
                float h = acc1[mf][nfl][i] + acc2[mf][nfl][i] * (1.0f / 2048.0f) + b1v[nfl];
                s = fmaf(gelu_exact(h), w2v[nfl], s);
            }
            int row = mf * 32 + (i & 3) + 8 * (i >> 2) + 4 * (lane >> 5);
            red[(w * 64 + row) * 33 + (lane & 31)] = s;
        }
    __syncthreads();
    float* sx = (float*)(smem + 67584);        // [64]
    if (t < 64) {
        float s = 0.f;
        for (int ww = 0; ww < 8; ++ww)
#pragma unroll
            for (int lc = 0; lc < 32; ++lc) s += red[(ww * 64 + t) * 33 + lc];
        sx[t] = s;
    }
    __syncthreads();
    if (t < 3 && jb * 3 + t < count) {
        int sg2 = flag_list[jb * 3 + t];
        const float* sv = sx + t * SEG_LEN;
        unsigned mask = 0;
        for (int it = 0; it < QUOTA; ++it) {
            float best = 0.f; int bi = 0; bool found = false;
            for (int i = 0; i < SEG_LEN; ++i) if (!((mask >> i) & 1u)) {
                if (!found || sv[i] > best) { best = sv[i]; bi = i; found = true; }
            }
            mask |= 1u << bi;
        }
        int c = 0;
        for (int i = 0; i < SEG_LEN; ++i)
            if ((mask >> i) & 1u) sel_buf[(size_t)sg2 * QUOTA + (c++)] = i;
    }
}

// ---- final gather of selected rows ----
__global__ void gather_kernel(const float* __restrict__ X, const int* __restrict__ sel_buf,
                              float* __restrict__ out, int N) {
    const int seg = blockIdx.x, b = blockIdx.y, t = threadIdx.x;
    const int* sel = sel_buf + ((size_t)b * N_SEG + seg) * QUOTA;
    const float4* xb = (const float4*)X + ((size_t)b * N + seg * SEG_LEN) * (H_DIM / 4);
    float4* ob = (float4*)out + ((size_t)b * N_SEG * QUOTA + seg * QUOTA) * (H_DIM / 4);
#pragma unroll
    for (int j = 0; j < QUOTA; ++j) {
        int r = sel[j];
        ob[(size_t)j * (H_DIM / 4) + t] = xb[(size_t)r * (H_DIM / 4) + t];
    }
}

extern "C" void kernel_launch(void* const* d_in, const int* in_sizes, int n_in,
                              void* d_out, int out_size, void* d_ws, size_t ws_size,
                              hipStream_t stream) {
    const float* X  = (const float*)d_in[0];
    const float* W1 = (const float*)d_in[1];
    const float* b1 = (const float*)d_in[2];
    const float* W2 = (const float*)d_in[3];
    float* out = (float*)d_out;

    const int Hh = in_sizes[2];                        // 512
    const int H  = Hh * 2;                             // 1024
    const long long TOT = (long long)in_sizes[0] / H;  // 147456 tokens
    const int B = 256;
    const int N = (int)(TOT / B);                      // 576
    const int nseg_tot = B * N_SEG;                    // 8192

    char* ws = (char*)d_ws;
    _Float16* B32 = (_Float16*)(ws + 0);               // 2 MB
    _Float16* B16 = (_Float16*)(ws + 2097152);         // 1 MB
    float* sparts = (float*)(ws + 3145728);            // 2*TOT f32
    int* sel_buf  = (int*)(ws + 4325376);              // 8192*9
    int* flag_list= (int*)(ws + 4620288);              // 8192
    int* counter  = (int*)(ws + 4653056);

    hipMemsetAsync(counter, 0, 16, stream);

    hipLaunchKernelGGL(pack_w1_kernel, dim3(512), dim3(256), 0, stream, W1, B32, B16);

    hipLaunchKernelGGL(stage1_kernel, dim3((unsigned)(TOT / 64), 2), dim3(256), 0, stream,
                       X, B16, b1, W2, sparts, (int)TOT);

    hipLaunchKernelGGL(flag_select_kernel, dim3((nseg_tot + 255) / 256), dim3(256), 0, stream,
                       sparts, (int)TOT, sel_buf, flag_list, counter, N, nseg_tot);

    hipLaunchKernelGGL(recheck_kernel, dim3((nseg_tot + 2) / 3), dim3(512), 0, stream,
                       X, B32, b1, W2, flag_list, counter, sel_buf, N);

    hipLaunchKernelGGL(gather_kernel, dim3(N_SEG, B), dim3(256), 0, stream,
                       X, sel_buf, out, N);
}